// Round 1
// baseline (1118.205 us; speedup 1.0000x reference)
//
#include <hip/hip_runtime.h>
#include <cstdint>
#include <cstddef>

#define P_TOT 114688   // N*H*W = 4*128*224
#define W_IMG 224
#define H_IMG 128

typedef _Float16 f16;
typedef __attribute__((ext_vector_type(8))) _Float16 f16x8;
typedef __attribute__((ext_vector_type(4))) _Float16 f16x4;
typedef __attribute__((ext_vector_type(2))) _Float16 f16x2;
typedef __attribute__((ext_vector_type(4))) float f32x4;

__device__ __forceinline__ void gload16(const void* g, void* l) {
  __builtin_amdgcn_global_load_lds((const __attribute__((address_space(1))) void*)g,
                                   (__attribute__((address_space(3))) void*)l, 16, 0, 0);
}

// ---------------- pack input: fp32 NCHW -> fp16 NHWC, chunk-swizzled -------------
// swizzle: within each aligned 32-channel group, 8-ch chunk index ^= (w&3)
__global__ void k_pack_x(const float* __restrict__ x, f16* __restrict__ xb) {
  int gid = blockIdx.x * 256 + threadIdx.x;           // total P_TOT*32
  if (gid >= P_TOT * 32) return;
  int c8 = gid & 31;
  int p  = gid >> 5;
  int w  = p % W_IMG;
  int h  = (p / W_IMG) % H_IMG;
  int n  = p / (H_IMG * W_IMG);
  const float* src = x + ((size_t)(n * 256 + c8 * 8) * H_IMG + h) * W_IMG + w;
  f16x8 v;
#pragma unroll
  for (int j = 0; j < 8; j++) v[j] = (f16)src[(size_t)j * (H_IMG * W_IMG)];
  int c8s = (c8 & ~3) | ((c8 ^ w) & 3);
  *(f16x8*)(xb + (size_t)p * 256 + c8s * 8) = v;
}

// ---------------- pack weights into [kk][CS/32][OT][32], swizzled by (o&3) -------
// mode 0: L1 (real input)  rows [w1r;w1i]
// mode 1: complex          rows [wr,-wi ; wi,wr]
// mode 2: head             rows wc, wg0, wg1, 0...
__global__ void k_pack_w(const float* __restrict__ wa, const float* __restrict__ wb,
                         f16* __restrict__ dst, int mode, int OT, int CS,
                         int Coh, int Cih, int total) {
  int gid = blockIdx.x * 256 + threadIdx.x;
  if (gid >= total) return;
  int j  = gid & 31;
  int t1 = gid >> 5;
  int o  = t1 % OT;
  int t2 = t1 / OT;
  int CCc = CS >> 5;
  int cc = t2 % CCc;
  int kk = t2 / CCc;
  int chunkT = ((j >> 3) ^ (o & 3)) & 3;   // unswizzle: stored chunk' holds true chunk'^(o&3)
  int is = cc * 32 + chunkT * 8 + (j & 7);
  float val = 0.f;
  if (mode == 0) {
    val = (o < Coh) ? wa[((size_t)o * Cih + is) * 9 + kk]
                    : wb[((size_t)(o - Coh) * Cih + is) * 9 + kk];
  } else if (mode == 1) {
    if (o < Coh) {
      val = (is < Cih) ? wa[((size_t)o * Cih + is) * 9 + kk]
                       : -wb[((size_t)o * Cih + (is - Cih)) * 9 + kk];
    } else {
      int oo = o - Coh;
      val = (is < Cih) ? wb[((size_t)oo * Cih + is) * 9 + kk]
                       : wa[((size_t)oo * Cih + (is - Cih)) * 9 + kk];
    }
  } else {
    if (o == 0)      val = wa[(size_t)is * 9 + kk];
    else if (o == 1) val = wb[(size_t)is * 9 + kk];
    else if (o == 2) val = wb[(size_t)(96 + is) * 9 + kk];
  }
  dst[gid] = (f16)val;
}

// ---------------- implicit-GEMM conv, MFMA fp16, double-buffered LDS -------------
// C[o][pixel] over one image row (224 px). BM=96 (OT/BM o-tiles), K = 9*CS.
template<int BM, int OT, int CS, int WM, int WN, bool HEAD>
__launch_bounds__(WM * WN * 64, 1)
__global__ void k_gemm(const f16* __restrict__ xb, const f16* __restrict__ Apack,
                       const char* __restrict__ zerop,
                       f16* __restrict__ y, float* __restrict__ outh,
                       const float* __restrict__ bcp, const float* __restrict__ bgp) {
  constexpr int NT = WM * WN * 64;
  constexpr int CC = CS / 32;
  constexpr int MF = BM / (WM * 16);
  constexpr int NF = 224 / (WN * 16);
  constexpr int STEPS = 9 * CC;
  constexpr int TILE = (BM + 224) * 32;   // f16 elements per buffer (A then B)
  __shared__ f16 lds[2][TILE];

  const int nwg = (OT / BM) * 512;
  int bid = blockIdx.x;
  int swz = (bid & 7) * (nwg >> 3) + (bid >> 3);  // XCD swizzle (nwg % 8 == 0)
  const int r  = swz & 511;
  const int ot = swz >> 9;
  const int n = r >> 7;
  const int h = r & 127;
  const int tid  = threadIdx.x;
  const int lane = tid & 63;
  const int wv   = tid >> 6;
  const int wm   = wv % WM;
  const int wn   = wv / WM;
  const int obase  = wm * (MF * 16);
  const int wnbase = wn * (NF * 16);
  const int l15 = lane & 15;
  const int lhi = lane >> 4;
  const int aoff = l15 * 64 + ((lhi ^ (lane & 3)) << 4);   // swizzled A frag offset

  f32x4 acc[MF][NF];
#pragma unroll
  for (int mi = 0; mi < MF; mi++)
#pragma unroll
    for (int ni = 0; ni < NF; ni++) acc[mi][ni] = (f32x4){0.f, 0.f, 0.f, 0.f};

  const size_t rowstride = (size_t)CS * 2;   // bytes per pixel in xb

  auto stage = [&](int buf, int kk, int c) {
    { // A tile: BM*64 bytes contiguous (pre-swizzled in Apack)
      const char* asrc = (const char*)(Apack + ((size_t)(kk * CC + c) * OT + ot * BM) * 32);
      char* adst = (char*)&lds[buf][0];
      for (int b2 = wv * 64; b2 < BM * 4; b2 += NT)
        gload16(asrc + (size_t)(b2 + lane) * 16, adst + b2 * 16);
    }
    { // B tile: 224 px * 64B (one 32-ch chunk), verbatim copy (already swizzled)
      const int dh = kk / 3 - 1;
      const int dw = kk % 3 - 1;
      const int hp = h + dh;
      const bool hok = (hp >= 0) && (hp < H_IMG);
      const int hpc = hok ? hp : 0;
      const char* brow = (const char*)xb + ((size_t)(n * H_IMG + hpc) * W_IMG) * rowstride + c * 64;
      char* bdst = (char*)&lds[buf][BM * 32];
      for (int b2 = wv * 64; b2 < 896; b2 += NT) {
        int idx = b2 + lane;
        int w  = idx >> 2, ch = idx & 3;
        int wp = w + dw;
        bool ok = hok && ((unsigned)wp < 224u);
        const char* src = ok ? brow + (size_t)(ok ? wp : 0) * rowstride + ch * 16
                             : zerop + ch * 16;
        gload16(src, bdst + b2 * 16);
      }
    }
  };

  auto compute = [&](int buf, int kk) {
    const int dw = kk % 3 - 1;
    const int bkey = ((lane & 3) + dw) & 3;     // stored-chunk key = (w'&3)
    const char* Ab = (const char*)&lds[buf][0];
    const char* Bb = (const char*)&lds[buf][BM * 32];
    f16x8 af[MF], bfr[NF];
#pragma unroll
    for (int mi = 0; mi < MF; mi++)
      af[mi] = *(const f16x8*)(Ab + (obase + mi * 16) * 64 + aoff);
#pragma unroll
    for (int ni = 0; ni < NF; ni++) {
      int rowb = (wnbase + ni * 16 + l15) * 64;
      int sw = ((lhi ^ bkey) & 3) << 4;
      bfr[ni] = *(const f16x8*)(Bb + rowb + sw);
    }
#pragma unroll
    for (int mi = 0; mi < MF; mi++)
#pragma unroll
      for (int ni = 0; ni < NF; ni++)
        acc[mi][ni] = __builtin_amdgcn_mfma_f32_16x16x32_f16(af[mi], bfr[ni], acc[mi][ni], 0, 0, 0);
  };

  stage(0, 0, 0);
  __syncthreads();
  int buf = 0, kk = 0, c = 0;
  for (int t = 0; t < STEPS; ++t) {
    int kn = kk, cn = c + 1;
    if (cn == CC) { cn = 0; kn++; }
    if (t + 1 < STEPS) stage(buf ^ 1, kn, cn);
    compute(buf, kk);
    __syncthreads();
    buf ^= 1; kk = kn; c = cn;
  }

  const size_t prow = (size_t)(n * H_IMG + h) * W_IMG;
  if constexpr (!HEAD) {
#pragma unroll
    for (int mi = 0; mi < MF; mi++) {
#pragma unroll
      for (int ni = 0; ni < NF; ni++) {
        int o = obase + mi * 16 + lhi * 4;
        int w = wnbase + ni * 16 + l15;
        f16x4 v4;
#pragma unroll
        for (int j = 0; j < 4; j++) v4[j] = (f16)acc[mi][ni][j];
        *(f16x4*)(y + (prow + w) * OT + ot * BM + o) = v4;
      }
    }
  } else {
    if (lhi == 0) {
      float b0 = bcp[0], b1 = bgp[0], b2 = bgp[1];
#pragma unroll
      for (int ni = 0; ni < NF; ni++) {
        int w = wnbase + ni * 16 + l15;
        float c0 = acc[0][ni][0] + b0;
        c0 = 1.f / (1.f + expf(-c0));
        float c1 = acc[0][ni][1] + b1;
        float c2 = acc[0][ni][2] + b2;
        outh[((size_t)(n * 3 + 0) * H_IMG + h) * W_IMG + w] = c0;
        outh[((size_t)(n * 3 + 1) * H_IMG + h) * W_IMG + w] = c1;
        outh[((size_t)(n * 3 + 2) * H_IMG + h) * W_IMG + w] = c2;
      }
    }
  }
}

// ---------------- BN stats: per-channel sum / sumsq over all pixels --------------
template<int O>
__global__ void k_stats(const f16* __restrict__ y, float* __restrict__ sums,
                        float* __restrict__ sumsq) {
  int r = blockIdx.x;            // 512 row-blocks of 224 px
  int t = threadIdx.x;
  if (t >= O / 2) return;
  const f16x2* base = (const f16x2*)(y + (size_t)r * 224 * O) + t;
  float s0 = 0, s1 = 0, q0 = 0, q1 = 0;
#pragma unroll 4
  for (int p = 0; p < 224; p++) {
    f16x2 u = base[p * (O / 2)];
    float a = (float)u[0], b = (float)u[1];
    s0 += a; q0 += a * a; s1 += b; q1 += b * b;
  }
  atomicAdd(&sums[2 * t], s0);  atomicAdd(&sums[2 * t + 1], s1);
  atomicAdd(&sumsq[2 * t], q0); atomicAdd(&sumsq[2 * t + 1], q1);
}

__global__ void k_finalize(const float* __restrict__ sums, const float* __restrict__ sumsq,
                           const float* __restrict__ g, const float* __restrict__ b,
                           float* __restrict__ scale, float* __restrict__ shift,
                           int O, int Half) {
  int t = threadIdx.x;
  if (t >= O) return;
  const float inv = 1.0f / (float)P_TOT;
  float mean = sums[t] * inv;
  float var  = fmaxf(sumsq[t] * inv - mean * mean, 0.f);
  int gi = (t < Half) ? t : (t - Half);
  float sc = g[gi] * rsqrtf(var + 1e-5f);
  scale[t] = sc;
  shift[t] = b[gi] - mean * sc;
}

// ---------------- in-place BN + ReLU + chunk-swizzle (prep next GEMM input) -----
template<int O>
__global__ void k_packip(f16* __restrict__ y, const float* __restrict__ scale,
                         const float* __restrict__ shift) {
  constexpr int G32 = O / 32;
  int gid = blockIdx.x * 256 + threadIdx.x;
  if (gid >= P_TOT * G32) return;
  int g = gid % G32;
  int p = gid / G32;
  int w = p % W_IMG;
  f16* base = y + (size_t)p * O + g * 32;
  f16x8 in[4];
#pragma unroll
  for (int ch = 0; ch < 4; ch++) in[ch] = *(const f16x8*)(base + ch * 8);
  int sw = w & 3;
  f16x8 outv[4];
#pragma unroll
  for (int ch = 0; ch < 4; ch++) {
#pragma unroll
    for (int j = 0; j < 8; j++) {
      int cdx = g * 32 + ch * 8 + j;
      float f = fmaxf(fmaf((float)in[ch][j], scale[cdx], shift[cdx]), 0.f);
      outv[ch][j] = (f16)f;
    }
  }
#pragma unroll
  for (int ch = 0; ch < 4; ch++) *(f16x8*)(base + ((ch ^ sw) & 3) * 8) = outv[ch];
}

// ---------------- BN(L4) + ReLU + complex magnitude -> 96ch swizzled ------------
__global__ void k_mag(const f16* __restrict__ y, const float* __restrict__ scale,
                      const float* __restrict__ shift, f16* __restrict__ mg) {
  int gid = blockIdx.x * 256 + threadIdx.x;
  if (gid >= P_TOT * 12) return;
  int c8 = gid % 12;
  int p  = gid / 12;
  int w  = p % W_IMG;
  f16x8 r8 = *(const f16x8*)(y + (size_t)p * 192 + c8 * 8);
  f16x8 i8 = *(const f16x8*)(y + (size_t)p * 192 + 96 + c8 * 8);
  f16x8 outv;
#pragma unroll
  for (int j = 0; j < 8; j++) {
    int cdx = c8 * 8 + j;
    float rr = fmaxf(fmaf((float)r8[j], scale[cdx], shift[cdx]), 0.f);
    float ii = fmaxf(fmaf((float)i8[j], scale[96 + cdx], shift[96 + cdx]), 0.f);
    outv[j] = (f16)sqrtf(rr * rr + ii * ii);
  }
  int c8s = (c8 & ~3) | ((c8 ^ w) & 3);
  *(f16x8*)(mg + (size_t)p * 96 + c8s * 8) = outv;
}

// ------------------------------------------------------------------------------
extern "C" void kernel_launch(void* const* d_in, const int* in_sizes, int n_in,
                              void* d_out, int out_size, void* d_ws, size_t ws_size,
                              hipStream_t stream) {
  const float* x   = (const float*)d_in[0];
  const float* w1r = (const float*)d_in[1];
  const float* w1i = (const float*)d_in[2];
  const float* g1  = (const float*)d_in[3];
  const float* b1  = (const float*)d_in[4];
  const float* w2r = (const float*)d_in[5];
  const float* w2i = (const float*)d_in[6];
  const float* g2  = (const float*)d_in[7];
  const float* b2  = (const float*)d_in[8];
  const float* w3r = (const float*)d_in[9];
  const float* w3i = (const float*)d_in[10];
  const float* g3  = (const float*)d_in[11];
  const float* b3  = (const float*)d_in[12];
  const float* w4r = (const float*)d_in[13];
  const float* w4i = (const float*)d_in[14];
  const float* g4  = (const float*)d_in[15];
  const float* b4  = (const float*)d_in[16];
  const float* wc  = (const float*)d_in[17];
  const float* bcp = (const float*)d_in[18];
  const float* wg  = (const float*)d_in[19];
  const float* bgp = (const float*)d_in[20];
  float* out = (float*)d_out;

  char* ws = (char*)d_ws;
  if (ws_size < 137500000ULL) return;  // need ~137.4 MB

  char* zerop = ws;                              // 16KB zero page
  auto S  = [&](int L) { return (float*)(ws + 16384 + L * 4096); };
  auto Q  = [&](int L) { return (float*)(ws + 16384 + L * 4096) + 512; };
  auto SC = [&](int L) { return (float*)(ws + 32768 + L * 4096); };
  auto SH = [&](int L) { return (float*)(ws + 32768 + L * 4096) + 512; };
  f16* A1 = (f16*)(ws + 65536);          // 663552 el
  f16* A2 = (f16*)(ws + 1392640);        // 497664 el
  f16* A3 = (f16*)(ws + 2387968);        // 331776 el
  f16* A4 = (f16*)(ws + 3051520);        // 331776 el
  f16* AH = (f16*)(ws + 3715072);        // 13824 el
  f16* XB0 = (f16*)(ws + (8ULL << 20));  // 58.7MB slab
  f16* Y   = (f16*)(ws + (68ULL << 20)); // 66MB slab

  hipMemsetAsync(d_ws, 0, 49152, stream);  // zero page + stats sums

  k_pack_x<<<P_TOT * 32 / 256, 256, 0, stream>>>(x, XB0);
  k_pack_w<<<(663552 + 255) / 256, 256, 0, stream>>>(w1r, w1i, A1, 0, 288, 256, 144, 256, 663552);
  k_pack_w<<<(497664 + 255) / 256, 256, 0, stream>>>(w2r, w2i, A2, 1, 192, 288, 96, 144, 497664);
  k_pack_w<<<(331776 + 255) / 256, 256, 0, stream>>>(w3r, w3i, A3, 1, 192, 192, 96, 96, 331776);
  k_pack_w<<<(331776 + 255) / 256, 256, 0, stream>>>(w4r, w4i, A4, 1, 192, 192, 96, 96, 331776);
  k_pack_w<<<(13824 + 255) / 256, 256, 0, stream>>>(wc, wg, AH, 2, 16, 96, 0, 96, 13824);

  // L1: 256 -> 288
  k_gemm<96, 288, 256, 2, 2, false><<<1536, 256, 0, stream>>>(XB0, A1, zerop, Y, nullptr, nullptr, nullptr);
  k_stats<288><<<512, 256, 0, stream>>>(Y, S(0), Q(0));
  k_finalize<<<1, 512, 0, stream>>>(S(0), Q(0), g1, b1, SC(0), SH(0), 288, 144);
  k_packip<288><<<P_TOT * 9 / 256, 256, 0, stream>>>(Y, SC(0), SH(0));

  // L2: 288 -> 192
  k_gemm<96, 192, 288, 2, 2, false><<<1024, 256, 0, stream>>>(Y, A2, zerop, XB0, nullptr, nullptr, nullptr);
  k_stats<192><<<512, 256, 0, stream>>>(XB0, S(1), Q(1));
  k_finalize<<<1, 512, 0, stream>>>(S(1), Q(1), g2, b2, SC(1), SH(1), 192, 96);
  k_packip<192><<<P_TOT * 6 / 256, 256, 0, stream>>>(XB0, SC(1), SH(1));

  // L3: 192 -> 192
  k_gemm<96, 192, 192, 2, 2, false><<<1024, 256, 0, stream>>>(XB0, A3, zerop, Y, nullptr, nullptr, nullptr);
  k_stats<192><<<512, 256, 0, stream>>>(Y, S(2), Q(2));
  k_finalize<<<1, 512, 0, stream>>>(S(2), Q(2), g3, b3, SC(2), SH(2), 192, 96);
  k_packip<192><<<P_TOT * 6 / 256, 256, 0, stream>>>(Y, SC(2), SH(2));

  // L4: 192 -> 192
  k_gemm<96, 192, 192, 2, 2, false><<<1024, 256, 0, stream>>>(Y, A4, zerop, XB0, nullptr, nullptr, nullptr);
  k_stats<192><<<512, 256, 0, stream>>>(XB0, S(3), Q(3));
  k_finalize<<<1, 512, 0, stream>>>(S(3), Q(3), g4, b4, SC(3), SH(3), 192, 96);

  // BN+ReLU+magnitude -> 96ch head input
  k_mag<<<P_TOT * 12 / 256, 256, 0, stream>>>(XB0, SC(3), SH(3), Y);

  // head: 96 -> 3 (sigmoid on ch0), writes NCHW fp32 output
  k_gemm<16, 16, 96, 1, 2, true><<<512, 128, 0, stream>>>(Y, AH, zerop, nullptr, out, bcp, bgp);

  (void)in_sizes; (void)n_in; (void)out_size;
}

// Round 2
// 1021.500 us; speedup vs baseline: 1.0947x; 1.0947x over previous
//
#include <hip/hip_runtime.h>
#include <cstdint>
#include <cstddef>

#define P_TOT 114688   // N*H*W = 4*128*224
#define W_IMG 224
#define H_IMG 128

typedef _Float16 f16;
typedef __attribute__((ext_vector_type(8))) _Float16 f16x8;
typedef __attribute__((ext_vector_type(4))) _Float16 f16x4;
typedef __attribute__((ext_vector_type(2))) _Float16 f16x2;
typedef __attribute__((ext_vector_type(4))) float f32x4;

#define WAITVM(N) asm volatile("s_waitcnt vmcnt(" #N ")" ::: "memory")

__device__ __forceinline__ void barrier_sync() {
  asm volatile("" ::: "memory");
  __builtin_amdgcn_s_barrier();
  asm volatile("" ::: "memory");
}

__device__ __forceinline__ void gload16(const void* g, void* l) {
  __builtin_amdgcn_global_load_lds((const __attribute__((address_space(1))) void*)g,
                                   (__attribute__((address_space(3))) void*)l, 16, 0, 0);
}

// ---------------- pack input: fp32 NCHW -> fp16 NHWC, chunk-swizzled -------------
// swizzle: within each aligned 32-channel group, 8-ch chunk index ^= (w&3)
__global__ void k_pack_x(const float* __restrict__ x, f16* __restrict__ xb) {
  int gid = blockIdx.x * 256 + threadIdx.x;           // total P_TOT*32
  if (gid >= P_TOT * 32) return;
  int c8 = gid & 31;
  int p  = gid >> 5;
  int w  = p % W_IMG;
  int h  = (p / W_IMG) % H_IMG;
  int n  = p / (H_IMG * W_IMG);
  const float* src = x + ((size_t)(n * 256 + c8 * 8) * H_IMG + h) * W_IMG + w;
  f16x8 v;
#pragma unroll
  for (int j = 0; j < 8; j++) v[j] = (f16)src[(size_t)j * (H_IMG * W_IMG)];
  int c8s = (c8 & ~3) | ((c8 ^ w) & 3);
  *(f16x8*)(xb + (size_t)p * 256 + c8s * 8) = v;
}

// ---------------- pack weights into [kk][CS/32][OT][32], swizzled by (o&3) -------
__global__ void k_pack_w(const float* __restrict__ wa, const float* __restrict__ wb,
                         f16* __restrict__ dst, int mode, int OT, int CS,
                         int Coh, int Cih, int total) {
  int gid = blockIdx.x * 256 + threadIdx.x;
  if (gid >= total) return;
  int j  = gid & 31;
  int t1 = gid >> 5;
  int o  = t1 % OT;
  int t2 = t1 / OT;
  int CCc = CS >> 5;
  int cc = t2 % CCc;
  int kk = t2 / CCc;
  int chunkT = ((j >> 3) ^ (o & 3)) & 3;
  int is = cc * 32 + chunkT * 8 + (j & 7);
  float val = 0.f;
  if (mode == 0) {
    val = (o < Coh) ? wa[((size_t)o * Cih + is) * 9 + kk]
                    : wb[((size_t)(o - Coh) * Cih + is) * 9 + kk];
  } else if (mode == 1) {
    if (o < Coh) {
      val = (is < Cih) ? wa[((size_t)o * Cih + is) * 9 + kk]
                       : -wb[((size_t)o * Cih + (is - Cih)) * 9 + kk];
    } else {
      int oo = o - Coh;
      val = (is < Cih) ? wb[((size_t)oo * Cih + is) * 9 + kk]
                       : wa[((size_t)oo * Cih + (is - Cih)) * 9 + kk];
    }
  } else {
    if (o == 0)      val = wa[(size_t)is * 9 + kk];
    else if (o == 1) val = wb[(size_t)is * 9 + kk];
    else if (o == 2) val = wb[(size_t)(96 + is) * 9 + kk];
  }
  dst[gid] = (f16)val;
}

// ---------------- implicit-GEMM conv, MFMA fp16, 3-deep ring LDS ----------------
template<int BM, int OT, int CS, int WM, int WN, bool HEAD>
__launch_bounds__(WM * WN * 64, 1)
__global__ void k_gemm(const f16* __restrict__ xb, const f16* __restrict__ Apack,
                       const char* __restrict__ zerop,
                       f16* __restrict__ y, float* __restrict__ outh,
                       const float* __restrict__ bcp, const float* __restrict__ bgp,
                       float* __restrict__ sums, float* __restrict__ sumsq) {
  constexpr int NT = WM * WN * 64;
  constexpr int NWV = NT / 64;
  constexpr int CC = CS / 32;
  constexpr int MF = BM / (WM * 16);
  constexpr int NF = 224 / (WN * 16);
  constexpr int STEPS = 9 * CC;
  constexpr int TILE = (BM + 224) * 32;   // f16 per buffer (A then B)
  constexpr int ACH = BM / 16;            // A 1KB-chunks
  constexpr int TCH = ACH + 14;           // total 1KB-chunks per stage
  constexpr int NBUF = HEAD ? 2 : 3;
  static_assert(HEAD || (TCH % NWV == 0 && TCH / NWV == 5), "vmcnt math assumes 5 loads/thread");
  __shared__ f16 lds[NBUF][TILE];

  constexpr int NOT = OT / BM;
  constexpr int nwg = NOT * 512;
  int bid = blockIdx.x;
  int swz = (bid & 7) * (nwg >> 3) + (bid >> 3);  // XCD swizzle (nwg % 8 == 0)
  const int ot = swz % NOT;                        // ot fastest -> same-B blocks adjacent
  const int rq = swz / NOT;
  const int n = rq >> 7;
  const int h = rq & 127;
  const int tid  = threadIdx.x;
  const int lane = tid & 63;
  const int wv   = tid >> 6;
  const int wm   = wv % WM;
  const int wn   = wv / WM;
  const int obase  = wm * (MF * 16);
  const int wnbase = wn * (NF * 16);
  const int l15 = lane & 15;
  const int lhi = lane >> 4;
  const int aoff = l15 * 64 + ((lhi ^ (lane & 3)) << 4);

  f32x4 acc[MF][NF];
#pragma unroll
  for (int mi = 0; mi < MF; mi++)
#pragma unroll
    for (int ni = 0; ni < NF; ni++) acc[mi][ni] = (f32x4){0.f, 0.f, 0.f, 0.f};

  const size_t rowstride = (size_t)CS * 2;   // bytes per pixel in xb

  auto stage = [&](int buf, int kk, int c) {
    const char* asrc = (const char*)(Apack + ((size_t)(kk * CC + c) * OT + ot * BM) * 32);
    const int dh = kk / 3 - 1;
    const int dw = kk % 3 - 1;
    const int hp = h + dh;
    const bool hok = (hp >= 0) && (hp < H_IMG);
    const int hpc = hok ? hp : 0;
    const char* brow = (const char*)xb + ((size_t)(n * H_IMG + hpc) * W_IMG) * rowstride + c * 64;
    char* base = (char*)&lds[buf][0];
#pragma unroll
    for (int ck = wv; ck < TCH; ck += NWV) {
      char* dst = base + ck * 1024;           // wave-uniform
      if (ck < ACH) {
        gload16(asrc + ck * 1024 + lane * 16, dst);
      } else {
        int bidx = ck - ACH;
        int px = bidx * 16 + (lane >> 2);
        int ch = lane & 3;
        int wp = px + dw;
        bool ok = hok && ((unsigned)wp < 224u);
        const char* src = ok ? brow + (size_t)wp * rowstride + ch * 16
                             : zerop + ch * 16;
        gload16(src, dst);
      }
    }
  };

  auto compute = [&](int buf, int kk) {
    const int dw = kk % 3 - 1;
    const int bkey = ((lane & 3) + dw) & 3;
    const char* Ab = (const char*)&lds[buf][0];
    const char* Bb = (const char*)&lds[buf][BM * 32];
    f16x8 af[MF], bfr[NF];
#pragma unroll
    for (int mi = 0; mi < MF; mi++)
      af[mi] = *(const f16x8*)(Ab + (obase + mi * 16) * 64 + aoff);
#pragma unroll
    for (int ni = 0; ni < NF; ni++) {
      int rowb = (wnbase + ni * 16 + l15) * 64;
      int sw = ((lhi ^ bkey) & 3) << 4;
      bfr[ni] = *(const f16x8*)(Bb + rowb + sw);
    }
#pragma unroll
    for (int mi = 0; mi < MF; mi++)
#pragma unroll
      for (int ni = 0; ni < NF; ni++)
        acc[mi][ni] = __builtin_amdgcn_mfma_f32_16x16x32_f16(af[mi], bfr[ni], acc[mi][ni], 0, 0, 0);
  };

  if constexpr (!HEAD) {
    // 3-deep ring, counted vmcnt (5 loads/thread/stage)
    stage(0, 0, 0);
    stage(1, 0, 1);
    for (int t = 0; t < STEPS; ++t) {
      int ts = t + 2;
      if (ts < STEPS) stage(ts % 3, ts / CC, ts % CC);
      if (ts < STEPS)           WAITVM(10);
      else if (t + 1 < STEPS)   WAITVM(5);
      else                      WAITVM(0);
      barrier_sync();
      compute(t % 3, t / CC);
      barrier_sync();
    }
  } else {
    stage(0, 0, 0);
    __syncthreads();
    int buf = 0;
    for (int t = 0; t < STEPS; ++t) {
      int tn = t + 1;
      if (tn < STEPS) stage(buf ^ 1, tn / CC, tn % CC);
      compute(buf, t / CC);
      __syncthreads();
      buf ^= 1;
    }
  }

  const size_t prow = (size_t)(n * H_IMG + h) * W_IMG;
  if constexpr (!HEAD) {
    // store fp16 NHWC output
#pragma unroll
    for (int mi = 0; mi < MF; mi++) {
#pragma unroll
      for (int ni = 0; ni < NF; ni++) {
        int o = obase + mi * 16 + lhi * 4;
        int w = wnbase + ni * 16 + l15;
        f16x4 v4;
#pragma unroll
        for (int j = 0; j < 4; j++) v4[j] = (f16)acc[mi][ni][j];
        *(f16x4*)(y + (prow + w) * OT + ot * BM + o) = v4;
      }
    }
    // fused BN stats: per-channel sum / sumsq partials
    float sv[MF][4], qv[MF][4];
#pragma unroll
    for (int mi = 0; mi < MF; mi++)
#pragma unroll
      for (int j = 0; j < 4; j++) {
        float s = 0.f, q = 0.f;
#pragma unroll
        for (int ni = 0; ni < NF; ni++) {
          float v = acc[mi][ni][j];
          s += v; q += v * v;
        }
        sv[mi][j] = s; qv[mi][j] = q;
      }
#pragma unroll
    for (int m = 1; m < 16; m <<= 1) {
#pragma unroll
      for (int mi = 0; mi < MF; mi++)
#pragma unroll
        for (int j = 0; j < 4; j++) {
          sv[mi][j] += __shfl_xor(sv[mi][j], m);
          qv[mi][j] += __shfl_xor(qv[mi][j], m);
        }
    }
    if (l15 == 0) {
#pragma unroll
      for (int mi = 0; mi < MF; mi++)
#pragma unroll
        for (int j = 0; j < 4; j++) {
          int ch = ot * BM + obase + mi * 16 + lhi * 4 + j;
          atomicAdd(&sums[ch], sv[mi][j]);
          atomicAdd(&sumsq[ch], qv[mi][j]);
        }
    }
  } else {
    if (lhi == 0) {
      float b0 = bcp[0], b1 = bgp[0], b2 = bgp[1];
#pragma unroll
      for (int ni = 0; ni < NF; ni++) {
        int w = wnbase + ni * 16 + l15;
        float c0 = acc[0][ni][0] + b0;
        c0 = 1.f / (1.f + expf(-c0));
        float c1 = acc[0][ni][1] + b1;
        float c2 = acc[0][ni][2] + b2;
        outh[((size_t)(n * 3 + 0) * H_IMG + h) * W_IMG + w] = c0;
        outh[((size_t)(n * 3 + 1) * H_IMG + h) * W_IMG + w] = c1;
        outh[((size_t)(n * 3 + 2) * H_IMG + h) * W_IMG + w] = c2;
      }
    }
  }
}

__global__ void k_finalize(const float* __restrict__ sums, const float* __restrict__ sumsq,
                           const float* __restrict__ g, const float* __restrict__ b,
                           float* __restrict__ scale, float* __restrict__ shift,
                           int O, int Half) {
  int t = threadIdx.x;
  if (t >= O) return;
  const float inv = 1.0f / (float)P_TOT;
  float mean = sums[t] * inv;
  float var  = fmaxf(sumsq[t] * inv - mean * mean, 0.f);
  int gi = (t < Half) ? t : (t - Half);
  float sc = g[gi] * rsqrtf(var + 1e-5f);
  scale[t] = sc;
  shift[t] = b[gi] - mean * sc;
}

// ---------------- in-place BN + ReLU + chunk-swizzle ----------------------------
template<int O>
__global__ void k_packip(f16* __restrict__ y, const float* __restrict__ scale,
                         const float* __restrict__ shift) {
  constexpr int G32 = O / 32;
  int gid = blockIdx.x * 256 + threadIdx.x;
  if (gid >= P_TOT * G32) return;
  int g = gid % G32;
  int p = gid / G32;
  int w = p % W_IMG;
  f16* base = y + (size_t)p * O + g * 32;
  f16x8 in[4];
#pragma unroll
  for (int ch = 0; ch < 4; ch++) in[ch] = *(const f16x8*)(base + ch * 8);
  int sw = w & 3;
  f16x8 outv[4];
#pragma unroll
  for (int ch = 0; ch < 4; ch++) {
#pragma unroll
    for (int j = 0; j < 8; j++) {
      int cdx = g * 32 + ch * 8 + j;
      float f = fmaxf(fmaf((float)in[ch][j], scale[cdx], shift[cdx]), 0.f);
      outv[ch][j] = (f16)f;
    }
  }
#pragma unroll
  for (int ch = 0; ch < 4; ch++) *(f16x8*)(base + ((ch ^ sw) & 3) * 8) = outv[ch];
}

// ---------------- BN(L4) + ReLU + complex magnitude -> 96ch swizzled ------------
__global__ void k_mag(const f16* __restrict__ y, const float* __restrict__ scale,
                      const float* __restrict__ shift, f16* __restrict__ mg) {
  int gid = blockIdx.x * 256 + threadIdx.x;
  if (gid >= P_TOT * 12) return;
  int c8 = gid % 12;
  int p  = gid / 12;
  int w  = p % W_IMG;
  f16x8 r8 = *(const f16x8*)(y + (size_t)p * 192 + c8 * 8);
  f16x8 i8 = *(const f16x8*)(y + (size_t)p * 192 + 96 + c8 * 8);
  f16x8 outv;
#pragma unroll
  for (int j = 0; j < 8; j++) {
    int cdx = c8 * 8 + j;
    float rr = fmaxf(fmaf((float)r8[j], scale[cdx], shift[cdx]), 0.f);
    float ii = fmaxf(fmaf((float)i8[j], scale[96 + cdx], shift[96 + cdx]), 0.f);
    outv[j] = (f16)sqrtf(rr * rr + ii * ii);
  }
  int c8s = (c8 & ~3) | ((c8 ^ w) & 3);
  *(f16x8*)(mg + (size_t)p * 96 + c8s * 8) = outv;
}

// ------------------------------------------------------------------------------
extern "C" void kernel_launch(void* const* d_in, const int* in_sizes, int n_in,
                              void* d_out, int out_size, void* d_ws, size_t ws_size,
                              hipStream_t stream) {
  const float* x   = (const float*)d_in[0];
  const float* w1r = (const float*)d_in[1];
  const float* w1i = (const float*)d_in[2];
  const float* g1  = (const float*)d_in[3];
  const float* b1  = (const float*)d_in[4];
  const float* w2r = (const float*)d_in[5];
  const float* w2i = (const float*)d_in[6];
  const float* g2  = (const float*)d_in[7];
  const float* b2  = (const float*)d_in[8];
  const float* w3r = (const float*)d_in[9];
  const float* w3i = (const float*)d_in[10];
  const float* g3  = (const float*)d_in[11];
  const float* b3  = (const float*)d_in[12];
  const float* w4r = (const float*)d_in[13];
  const float* w4i = (const float*)d_in[14];
  const float* g4  = (const float*)d_in[15];
  const float* b4  = (const float*)d_in[16];
  const float* wc  = (const float*)d_in[17];
  const float* bcp = (const float*)d_in[18];
  const float* wg  = (const float*)d_in[19];
  const float* bgp = (const float*)d_in[20];
  float* out = (float*)d_out;

  char* ws = (char*)d_ws;
  if (ws_size < 137500000ULL) return;

  char* zerop = ws;                              // 16KB zero page
  auto S  = [&](int L) { return (float*)(ws + 16384 + L * 4096); };
  auto Q  = [&](int L) { return (float*)(ws + 16384 + L * 4096) + 512; };
  auto SC = [&](int L) { return (float*)(ws + 32768 + L * 4096); };
  auto SH = [&](int L) { return (float*)(ws + 32768 + L * 4096) + 512; };
  f16* A1 = (f16*)(ws + 65536);
  f16* A2 = (f16*)(ws + 1392640);
  f16* A3 = (f16*)(ws + 2387968);
  f16* A4 = (f16*)(ws + 3051520);
  f16* AH = (f16*)(ws + 3715072);
  f16* XB0 = (f16*)(ws + (8ULL << 20));
  f16* Y   = (f16*)(ws + (68ULL << 20));

  hipMemsetAsync(d_ws, 0, 49152, stream);  // zero page + stats sums

  k_pack_x<<<P_TOT * 32 / 256, 256, 0, stream>>>(x, XB0);
  k_pack_w<<<(663552 + 255) / 256, 256, 0, stream>>>(w1r, w1i, A1, 0, 288, 256, 144, 256, 663552);
  k_pack_w<<<(497664 + 255) / 256, 256, 0, stream>>>(w2r, w2i, A2, 1, 192, 288, 96, 144, 497664);
  k_pack_w<<<(331776 + 255) / 256, 256, 0, stream>>>(w3r, w3i, A3, 1, 192, 192, 96, 96, 331776);
  k_pack_w<<<(331776 + 255) / 256, 256, 0, stream>>>(w4r, w4i, A4, 1, 192, 192, 96, 96, 331776);
  k_pack_w<<<(13824 + 255) / 256, 256, 0, stream>>>(wc, wg, AH, 2, 16, 96, 0, 96, 13824);

  // L1: 256 -> 288
  k_gemm<96, 288, 256, 2, 2, false><<<1536, 256, 0, stream>>>(XB0, A1, zerop, Y, nullptr, nullptr, nullptr, S(0), Q(0));
  k_finalize<<<1, 512, 0, stream>>>(S(0), Q(0), g1, b1, SC(0), SH(0), 288, 144);
  k_packip<288><<<P_TOT * 9 / 256, 256, 0, stream>>>(Y, SC(0), SH(0));

  // L2: 288 -> 192
  k_gemm<96, 192, 288, 2, 2, false><<<1024, 256, 0, stream>>>(Y, A2, zerop, XB0, nullptr, nullptr, nullptr, S(1), Q(1));
  k_finalize<<<1, 512, 0, stream>>>(S(1), Q(1), g2, b2, SC(1), SH(1), 192, 96);
  k_packip<192><<<P_TOT * 6 / 256, 256, 0, stream>>>(XB0, SC(1), SH(1));

  // L3: 192 -> 192
  k_gemm<96, 192, 192, 2, 2, false><<<1024, 256, 0, stream>>>(XB0, A3, zerop, Y, nullptr, nullptr, nullptr, S(2), Q(2));
  k_finalize<<<1, 512, 0, stream>>>(S(2), Q(2), g3, b3, SC(2), SH(2), 192, 96);
  k_packip<192><<<P_TOT * 6 / 256, 256, 0, stream>>>(Y, SC(2), SH(2));

  // L4: 192 -> 192
  k_gemm<96, 192, 192, 2, 2, false><<<1024, 256, 0, stream>>>(Y, A4, zerop, XB0, nullptr, nullptr, nullptr, S(3), Q(3));
  k_finalize<<<1, 512, 0, stream>>>(S(3), Q(3), g4, b4, SC(3), SH(3), 192, 96);

  // BN+ReLU+magnitude -> 96ch head input
  k_mag<<<P_TOT * 12 / 256, 256, 0, stream>>>(XB0, SC(3), SH(3), Y);

  // head: 96 -> 3 (sigmoid on ch0), writes NCHW fp32 output
  k_gemm<16, 16, 96, 1, 2, true><<<512, 128, 0, stream>>>(Y, AH, zerop, nullptr, out, bcp, bgp, nullptr, nullptr);

  (void)in_sizes; (void)n_in; (void)out_size;
}